// Round 11
// baseline (651.004 us; speedup 1.0000x reference)
//
#include <hip/hip_runtime.h>
#include <hip/hip_fp16.h>
#include <math.h>

#define BATCH 128
#define NTOK  343
#define NPAD  352
#define CDIM  384
#define NH    12
#define DH    32
#define NWIN  32
#define MTOK  (BATCH*NTOK)   // 43904
#define NN    (NTOK*NTOK)    // 117649
#define QKVF  (3*CDIM)       // 1152
#define KSTR  40             // attn K LDS row stride (halves)
#define VSTR  360
#define PSTR  106            // chunked P buffer stride (halves); conflict-free
#define MBW2  11             // u32 words per transposed mask row (bits over query i)

#define LOG2E 1.4426950408889634f

typedef float    f32x4 __attribute__((ext_vector_type(4)));
typedef _Float16 half8 __attribute__((ext_vector_type(8)));

#define LDS_K   (NPAD*KSTR)                 // 14080 halves = 28160 B
#define LDS_V   (DH*VSTR)                   // 11520 halves = 23040 B
#define LDS_P   (16*PSTR)                   // 1696 halves  = 3392 B per wave
#define LDS_TOT (LDS_K + LDS_V + 8*LDS_P)   // 39168 halves = 78336 B

// async global->LDS, 16B per lane; LDS dest = wave-uniform base + lane*16
__device__ __forceinline__ void gl2lds16(const __half* g, __half* l) {
  __builtin_amdgcn_global_load_lds(
      (const __attribute__((address_space(1))) void*)g,
      (__attribute__((address_space(3))) void*)l,
      16, 0, 0);
}

// ---------------- fp32 -> fp16 convert (8 elems/thread) ----------------
__global__ __launch_bounds__(256) void cvt_f16_k(
    const float* __restrict__ in, __half* __restrict__ out, int n) {
  int i = (blockIdx.x * 256 + threadIdx.x) * 8;
  if (i >= n) return;
  float4 a = *(const float4*)&in[i];
  float4 b = *(const float4*)&in[i + 4];
  half8 h;
  h[0] = (_Float16)a.x; h[1] = (_Float16)a.y; h[2] = (_Float16)a.z; h[3] = (_Float16)a.w;
  h[4] = (_Float16)b.x; h[5] = (_Float16)b.y; h[6] = (_Float16)b.z; h[7] = (_Float16)b.w;
  *(half8*)&out[i] = h;
}

// ---------------- bias gather to fp16 dense [h][i][j], pre-scaled by LOG2E ----
__global__ __launch_bounds__(256) void bias_expand_k(
    const int* __restrict__ rel_index, const float* __restrict__ table,
    __half* __restrict__ bias16) {
  int ij = blockIdx.x * 256 + threadIdx.x;
  if (ij >= NN) return;
  int idx = rel_index[ij];
#pragma unroll
  for (int hh = 0; hh < NH; ++hh)
    bias16[(size_t)hh * NN + ij] = __float2half(table[idx * NH + hh] * LOG2E);
}

// ---------------- transposed mask bits: mbt[w][key_j][word] over query-i bits --
// bit=1 where attention allowed; j>=343 rows all zero (kills padded keys).
__global__ __launch_bounds__(256) void mask_packt_k(
    const float* __restrict__ mask, unsigned int* __restrict__ mbt) {
  int t = blockIdx.x * 256 + threadIdx.x;
  if (t >= NWIN * NPAD * MBW2) return;
  int wi = t % MBW2;
  int j  = (t / MBW2) % NPAD;
  int w  = t / (MBW2 * NPAD);
  unsigned bits = 0u;
  if (j < NTOK) {
    const float* mp = mask + (size_t)w * NN + j;
#pragma unroll
    for (int bi = 0; bi < 32; ++bi) {
      int i = wi * 32 + bi;
      if (i < NTOK && mp[(size_t)i * NTOK] == 0.0f) bits |= (1u << bi);
    }
  }
  mbt[t] = bits;
}

// ---------------- MFMA GEMM (all-fp16 inputs, global_load_lds staging) --------
// C[m,f] = sum_k A[m,k]*B[f,k]; 128x128 tile, BK=32, 4 waves, m97 2-barrier loop.
// EPI 0: packed qkv fp16 store (q scaled by 32^-0.5 * LOG2E).  EPI 1: fp32 +bias.
template<int EPI>
__global__ __launch_bounds__(256) void gemm_mfma_k(
    const __half* __restrict__ Ah, const __half* __restrict__ Bh,
    const float* __restrict__ bias, void* __restrict__ Cv) {
  __shared__ __half As[128 * 32];
  __shared__ __half Bs[128 * 32];
  const int tid  = threadIdx.x;
  const int lane = tid & 63, wave = tid >> 6;
  const int lr = lane & 15, lg = lane >> 4;
  const int wr = wave >> 1, wc = wave & 1;
  const int n0 = blockIdx.x * 128;
  const int m0 = blockIdx.y * 128;
  const int KD = 384;

  f32x4 acc[4][4];
#pragma unroll
  for (int i = 0; i < 4; ++i)
#pragma unroll
    for (int j = 0; j < 4; ++j) acc[i][j] = (f32x4){0.f, 0.f, 0.f, 0.f};

  for (int k0 = 0; k0 < KD; k0 += 32) {
#pragma unroll
    for (int i = 0; i < 2; ++i) {
      int cb = wave * 128 + i * 64;          // wave-uniform chunk base
      int c  = cb + lane;
      int row = c & 127, kg = c >> 7;
      gl2lds16(&Ah[(size_t)(m0 + row) * KD + k0 + kg * 8], &As[cb * 8]);
      gl2lds16(&Bh[(size_t)(n0 + row) * KD + k0 + kg * 8], &Bs[cb * 8]);
    }
    __syncthreads();

    half8 af[4], bf[4];
#pragma unroll
    for (int t = 0; t < 4; ++t) {
      af[t] = *(const half8*)&As[(lg * 128 + wr * 64 + t * 16 + lr) * 8];
      bf[t] = *(const half8*)&Bs[(lg * 128 + wc * 64 + t * 16 + lr) * 8];
    }
#pragma unroll
    for (int mi = 0; mi < 4; ++mi)
#pragma unroll
      for (int ni = 0; ni < 4; ++ni)
        acc[mi][ni] = __builtin_amdgcn_mfma_f32_16x16x32_f16(af[mi], bf[ni], acc[mi][ni], 0, 0, 0);
    __syncthreads();
  }

#pragma unroll
  for (int mi = 0; mi < 4; ++mi) {
#pragma unroll
    for (int r = 0; r < 4; ++r) {
      int m = m0 + wr * 64 + mi * 16 + lg * 4 + r;
#pragma unroll
      for (int ni = 0; ni < 4; ++ni) {
        int f = n0 + wc * 64 + ni * 16 + lr;
        float v = acc[mi][ni][r];
        if (EPI == 0) {
          if (f < CDIM) v *= (0.17677669529663687f * LOG2E);   // q scale, log2 units
          ((__half*)Cv)[(size_t)m * QKVF + f] = __float2half(v);
        } else {
          ((float*)Cv)[(size_t)m * CDIM + f] = v + bias[f];
        }
      }
    }
  }
}

// ---------------- MFMA attention: 1 block per (b,h), 8 waves ----------------
// round-8 structure; changes: transposed mask (22 loads, multiplicative zeroing
// after exp2), exp2 rebase (q & bias pre-scaled by LOG2E), PSTR 106.
__global__ __launch_bounds__(512, 1) void attn_k(
    const __half* __restrict__ qkvh, const __half* __restrict__ bias16,
    const unsigned int* __restrict__ mbt, __half* __restrict__ av) {
  extern __shared__ __half smem[];
  __half* Ks = smem;                 // [NPAD][KSTR]
  __half* Vt = smem + LDS_K;         // [DH][VSTR]
  const int tid  = threadIdx.x;
  const int wave = tid >> 6, lane = tid & 63;
  const int lr   = lane & 15, lg = lane >> 4;
  __half* Pw = smem + LDS_K + LDS_V + wave * LDS_P;  // per-wave [16][PSTR]

  const int bh = blockIdx.x;
  const int b  = bh / NH, h = bh - b * NH;
  const int w  = b & (NWIN - 1);
  const size_t tbase = (size_t)b * NTOK;
  const int hoff = h * DH;

  for (int idx = tid; idx < NPAD * 4; idx += 512) {
    int j = idx >> 2, off = (idx & 3) << 3;
    half8 val = {0,0,0,0,0,0,0,0};
    if (j < NTOK) val = *reinterpret_cast<const half8*>(&qkvh[(tbase + j) * QKVF + CDIM + hoff + off]);
    *reinterpret_cast<half8*>(&Ks[j * KSTR + off]) = val;
  }
  for (int idx = tid; idx < NPAD * 4; idx += 512) {
    int j = idx >> 2, off = (idx & 3) << 3;
    if (j < NTOK) {
      union { float4 f; __half h[8]; } u;
      u.f = *reinterpret_cast<const float4*>(&qkvh[(tbase + j) * QKVF + 2 * CDIM + hoff + off]);
#pragma unroll
      for (int uu = 0; uu < 8; ++uu) Vt[(off + uu) * VSTR + j] = u.h[uu];
    } else {
#pragma unroll
      for (int uu = 0; uu < 8; ++uu) Vt[(off + uu) * VSTR + j] = __float2half(0.f);
    }
  }
  __syncthreads();

  const __half* bias_h = bias16 + (size_t)h * NN;            // [i][j], log2 units
  const unsigned int* mb_w = mbt + (size_t)w * NPAD * MBW2;  // [key_j][word_i]

  for (int i0 = wave * 16; i0 < NPAD; i0 += 128) {
    int qrow = min(i0 + lr, NTOK - 1);
    half8 qa = *reinterpret_cast<const half8*>(&qkvh[(tbase + qrow) * QKVF + hoff + lg * 8]);

    // QK^T: 22 j-tiles (q pre-scaled to log2 units)
    f32x4 s[22];
    const f32x4 zf = {0.f, 0.f, 0.f, 0.f};
#pragma unroll
    for (int jt = 0; jt < 22; ++jt) {
      half8 kb = *reinterpret_cast<const half8*>(&Ks[(jt * 16 + lr) * KSTR + lg * 8]);
      s[jt] = __builtin_amdgcn_mfma_f32_16x16x32_f16(qa, kb, zf, 0, 0, 0);
    }

    // mask words (transposed layout): independent of MFMA results, latency
    // hides under the bias fuse pass below
    const int wi = i0 >> 5;
    const unsigned shb = (unsigned)((i0 & 16) + lg * 4);
    unsigned mt[22];
#pragma unroll
    for (int jt = 0; jt < 22; ++jt)
      mt[jt] = mb_w[(jt * 16 + lr) * MBW2 + wi];

    int il[4];
#pragma unroll
    for (int r = 0; r < 4; ++r) il[r] = min(i0 + lg * 4 + r, NTOK - 1);

    // bias fuse (coalesced scalar loads, round-8 path; bias in log2 units)
#pragma unroll
    for (int jt = 0; jt < 22; ++jt) {
      int jl = min(jt * 16 + lr, NTOK - 1);
#pragma unroll
      for (int r = 0; r < 4; ++r) {
        float bm = __half2float(bias_h[(size_t)il[r] * NTOK + jl]);
        s[jt][r] += bm;
      }
    }

    // row max over unmasked scores (exact: any mx >= allowed max keeps ratios)
    float mx[4] = {-1e30f, -1e30f, -1e30f, -1e30f};
#pragma unroll
    for (int jt = 0; jt < 22; ++jt)
#pragma unroll
      for (int r = 0; r < 4; ++r) mx[r] = fmaxf(mx[r], s[jt][r]);
#pragma unroll
    for (int off = 1; off <= 8; off <<= 1)
#pragma unroll
      for (int r = 0; r < 4; ++r) mx[r] = fmaxf(mx[r], __shfl_xor(mx[r], off));

    // p = allowed ? exp2(s - mx) : 0
    float sm[4] = {0.f, 0.f, 0.f, 0.f};
#pragma unroll
    for (int jt = 0; jt < 22; ++jt) {
      unsigned mw = mt[jt] >> shb;
#pragma unroll
      for (int r = 0; r < 4; ++r) {
        float p = exp2f(s[jt][r] - mx[r]);
        p = ((mw >> r) & 1u) ? p : 0.f;
        s[jt][r] = p;
        sm[r] += p;
      }
    }
#pragma unroll
    for (int off = 1; off <= 8; off <<= 1)
#pragma unroll
      for (int r = 0; r < 4; ++r) sm[r] += __shfl_xor(sm[r], off);

    // chunked P->LDS + PV: 4 chunks of <=96 keys through a [16][106] buffer
    f32x4 o0 = {0.f, 0.f, 0.f, 0.f}, o1 = {0.f, 0.f, 0.f, 0.f};
#pragma unroll
    for (int c = 0; c < 4; ++c) {
      const int njt = (c < 3) ? 6 : 4;     // chunk 3 covers keys 288..351
#pragma unroll
      for (int jtl = 0; jtl < njt; ++jtl) {
        int jt = c * 6 + jtl;
#pragma unroll
        for (int r = 0; r < 4; ++r)
          Pw[(lg * 4 + r) * PSTR + jtl * 16 + lr] = __float2half(s[jt][r]);
      }
      asm volatile("s_waitcnt lgkmcnt(0)" ::: "memory");
      __builtin_amdgcn_sched_barrier(0);
      const int nkt = (c < 3) ? 3 : 2;
#pragma unroll
      for (int ktl = 0; ktl < nkt; ++ktl) {
        int ktg = c * 3 + ktl;
        half8 pa  = *reinterpret_cast<const half8*>(&Pw[lr * PSTR + ktl * 32 + lg * 8]);
        half8 vb0 = *reinterpret_cast<const half8*>(&Vt[lr * VSTR + ktg * 32 + lg * 8]);
        half8 vb1 = *reinterpret_cast<const half8*>(&Vt[(16 + lr) * VSTR + ktg * 32 + lg * 8]);
        o0 = __builtin_amdgcn_mfma_f32_16x16x32_f16(pa, vb0, o0, 0, 0, 0);
        o1 = __builtin_amdgcn_mfma_f32_16x16x32_f16(pa, vb1, o1, 0, 0, 0);
      }
    }

#pragma unroll
    for (int r = 0; r < 4; ++r) {
      int i = i0 + lg * 4 + r;
      if (i < NTOK) {
        float inv = 1.f / sm[r];
        size_t ob = ((size_t)b * NTOK + i) * CDIM + hoff;
        av[ob + lr]      = __float2half(o0[r] * inv);
        av[ob + 16 + lr] = __float2half(o1[r] * inv);
      }
    }
  }
}

extern "C" void kernel_launch(void* const* d_in, const int* in_sizes, int n_in,
                              void* d_out, int out_size, void* d_ws, size_t ws_size,
                              hipStream_t stream) {
  const float* x          = (const float*)d_in[0];
  const float* mask       = (const float*)d_in[4];
  const float* w_qkv      = (const float*)d_in[6];
  const float* bias_table = (const float*)d_in[7];
  const float* w_proj     = (const float*)d_in[8];
  const float* b_proj     = (const float*)d_in[9];
  const int*   rel_index  = (const int*)d_in[10];
  float* out = (float*)d_out;

  // ws (~139.5 MB): qkvh [MTOK][1152] fp16, avb [MTOK][384] fp16 (alias xh),
  // bias16 [12][NN] fp16, mbt [32][352][11] u32, wqkvh, wprojh
  __half* qkvh   = (__half*)d_ws;
  __half* avb    = qkvh + (size_t)MTOK * QKVF;
  __half* xh     = avb;                                  // alias
  __half* bias16 = avb + (size_t)MTOK * CDIM;
  unsigned int* mbt = (unsigned int*)(bias16 + (size_t)NH * NN);
  __half* wqkvh  = (__half*)(mbt + (size_t)NWIN * NPAD * MBW2);
  __half* wprojh = wqkvh + (size_t)QKVF * CDIM;

  const int NX = MTOK * CDIM;        // 16,859,136
  const int NWQ = QKVF * CDIM;       // 442,368
  const int NWP = CDIM * CDIM;       // 147,456
  cvt_f16_k<<<NX / 8 / 256, 256, 0, stream>>>(x, xh, NX);
  cvt_f16_k<<<NWQ / 8 / 256, 256, 0, stream>>>(w_qkv, wqkvh, NWQ);
  cvt_f16_k<<<NWP / 8 / 256, 256, 0, stream>>>(w_proj, wprojh, NWP);
  mask_packt_k<<<(NWIN * NPAD * MBW2 + 255) / 256, 256, 0, stream>>>(mask, mbt);
  bias_expand_k<<<(NN + 255) / 256, 256, 0, stream>>>(rel_index, bias_table, bias16);

  // QKV: A = xh, B = wqkvh, C = packed qkvh (fp16, q scaled to log2 units)
  gemm_mfma_k<0><<<dim3(QKVF / 128, MTOK / 128), 256, 0, stream>>>(
      xh, wqkvh, nullptr, qkvh);

  (void)hipFuncSetAttribute((const void*)attn_k,
                            hipFuncAttributeMaxDynamicSharedMemorySize, LDS_TOT * 2);
  attn_k<<<BATCH * NH, 512, LDS_TOT * 2, stream>>>(qkvh, bias16, mbt, avb);

  // proj: A = avb (fp16), B = wprojh, C = out (fp32 + bias)
  gemm_mfma_k<1><<<dim3(CDIM / 128, MTOK / 128), 256, 0, stream>>>(
      avb, wprojh, b_proj, out);
}

// Round 12
// 331.499 us; speedup vs baseline: 1.9638x; 1.9638x over previous
//
#include <hip/hip_runtime.h>
#include <hip/hip_fp16.h>
#include <math.h>

#define BATCH 128
#define NTOK  343
#define NPAD  352
#define CDIM  384
#define NH    12
#define DH    32
#define NWIN  32
#define MTOK  (BATCH*NTOK)   // 43904
#define NN    (NTOK*NTOK)    // 117649
#define QKVF  (3*CDIM)       // 1152
#define KSTR  40             // attn K LDS row stride (halves)
#define VSTR  360
#define PSTR  106            // chunked P buffer stride (halves); conflict-verified
#define MBW   11             // u32 words per packed mask row

typedef float    f32x4 __attribute__((ext_vector_type(4)));
typedef _Float16 half8 __attribute__((ext_vector_type(8)));

#define LDS_K   (NPAD*KSTR)                 // 14080 halves = 28160 B
#define LDS_V   (DH*VSTR)                   // 11520 halves = 23040 B
#define LDS_P   (16*PSTR)                   // 1696 halves  = 3392 B per wave
#define LDS_TOT (LDS_K + LDS_V + 8*LDS_P)   // 39168 halves = 78336 B (2 blocks/CU)

// async global->LDS, 16B per lane; LDS dest = wave-uniform base + lane*16
__device__ __forceinline__ void gl2lds16(const __half* g, __half* l) {
  __builtin_amdgcn_global_load_lds(
      (const __attribute__((address_space(1))) void*)g,
      (__attribute__((address_space(3))) void*)l,
      16, 0, 0);
}

// ---------------- fp32 -> fp16 convert (8 elems/thread) ----------------
__global__ __launch_bounds__(256) void cvt_f16_k(
    const float* __restrict__ in, __half* __restrict__ out, int n) {
  int i = (blockIdx.x * 256 + threadIdx.x) * 8;
  if (i >= n) return;
  float4 a = *(const float4*)&in[i];
  float4 b = *(const float4*)&in[i + 4];
  half8 h;
  h[0] = (_Float16)a.x; h[1] = (_Float16)a.y; h[2] = (_Float16)a.z; h[3] = (_Float16)a.w;
  h[4] = (_Float16)b.x; h[5] = (_Float16)b.y; h[6] = (_Float16)b.z; h[7] = (_Float16)b.w;
  *(half8*)&out[i] = h;
}

// ---------------- bias gather to fp16 dense [h][i][j] ----------------
__global__ __launch_bounds__(256) void bias_expand_k(
    const int* __restrict__ rel_index, const float* __restrict__ table,
    __half* __restrict__ bias16) {
  int ij = blockIdx.x * 256 + threadIdx.x;
  if (ij >= NN) return;
  int idx = rel_index[ij];
#pragma unroll
  for (int hh = 0; hh < NH; ++hh)
    bias16[(size_t)hh * NN + ij] = __float2half(table[idx * NH + hh]);
}

// ---------------- mask bit-pack: bit=1 where mask==0 (allowed) ----------------
__global__ __launch_bounds__(256) void mask_pack_k(
    const float* __restrict__ mask, unsigned int* __restrict__ mbits) {
  int row = blockIdx.x * 4 + (threadIdx.x >> 6);
  int lane = threadIdx.x & 63;
  if (row >= NWIN * NTOK) return;
  const float* mr = mask + (size_t)row * NTOK;
#pragma unroll
  for (int seg = 0; seg < 6; ++seg) {
    int j = seg * 64 + lane;
    bool allowed = (j < NTOK) ? (mr[j] == 0.0f) : false;
    unsigned long long bits = __ballot(allowed);
    if (lane == 0) mbits[(size_t)row * MBW + seg*2] = (unsigned)bits;
    if (lane == 1 && seg*2 + 1 < MBW) mbits[(size_t)row * MBW + seg*2 + 1] = (unsigned)(bits >> 32);
  }
}

// ---------------- MFMA GEMM (all-fp16 inputs, global_load_lds staging) --------
// C[m,f] = sum_k A[m,k]*B[f,k]; 128x128 tile, BK=32, 4 waves, m97 2-barrier loop.
// EPI 0: packed qkv fp16 store (scale cols f<384).  EPI 1: fp32 out = acc+bias.
template<int EPI>
__global__ __launch_bounds__(256) void gemm_mfma_k(
    const __half* __restrict__ Ah, const __half* __restrict__ Bh,
    const float* __restrict__ bias, void* __restrict__ Cv) {
  __shared__ __half As[128 * 32];
  __shared__ __half Bs[128 * 32];
  const int tid  = threadIdx.x;
  const int lane = tid & 63, wave = tid >> 6;
  const int lr = lane & 15, lg = lane >> 4;
  const int wr = wave >> 1, wc = wave & 1;
  const int n0 = blockIdx.x * 128;
  const int m0 = blockIdx.y * 128;
  const int KD = 384;

  f32x4 acc[4][4];
#pragma unroll
  for (int i = 0; i < 4; ++i)
#pragma unroll
    for (int j = 0; j < 4; ++j) acc[i][j] = (f32x4){0.f, 0.f, 0.f, 0.f};

  for (int k0 = 0; k0 < KD; k0 += 32) {
#pragma unroll
    for (int i = 0; i < 2; ++i) {
      int cb = wave * 128 + i * 64;          // wave-uniform chunk base
      int c  = cb + lane;
      int row = c & 127, kg = c >> 7;
      gl2lds16(&Ah[(size_t)(m0 + row) * KD + k0 + kg * 8], &As[cb * 8]);
      gl2lds16(&Bh[(size_t)(n0 + row) * KD + k0 + kg * 8], &Bs[cb * 8]);
    }
    __syncthreads();

    half8 af[4], bf[4];
#pragma unroll
    for (int t = 0; t < 4; ++t) {
      af[t] = *(const half8*)&As[(lg * 128 + wr * 64 + t * 16 + lr) * 8];
      bf[t] = *(const half8*)&Bs[(lg * 128 + wc * 64 + t * 16 + lr) * 8];
    }
#pragma unroll
    for (int mi = 0; mi < 4; ++mi)
#pragma unroll
      for (int ni = 0; ni < 4; ++ni)
        acc[mi][ni] = __builtin_amdgcn_mfma_f32_16x16x32_f16(af[mi], bf[ni], acc[mi][ni], 0, 0, 0);
    __syncthreads();
  }

#pragma unroll
  for (int mi = 0; mi < 4; ++mi) {
#pragma unroll
    for (int r = 0; r < 4; ++r) {
      int m = m0 + wr * 64 + mi * 16 + lg * 4 + r;
#pragma unroll
      for (int ni = 0; ni < 4; ++ni) {
        int f = n0 + wc * 64 + ni * 16 + lr;
        float v = acc[mi][ni][r];
        if (EPI == 0) {
          if (f < CDIM) v *= 0.17677669529663687f;   // q scale
          ((__half*)Cv)[(size_t)m * QKVF + f] = __float2half(v);
        } else {
          ((float*)Cv)[(size_t)m * CDIM + f] = v + bias[f];
        }
      }
    }
  }
}

// ---------------- MFMA attention: 1 block per (b,h), 8 waves ----------------
// round-8 base; ONLY structural change: flash-style online softmax chunked
// along the existing 4-chunk P->PV pipeline. Cuts live score regs 88 -> 24
// so 4 waves/SIMD + 2 blocks/CU can co-reside.
__global__ __launch_bounds__(512, 1) void attn_k(
    const __half* __restrict__ qkvh, const __half* __restrict__ bias16,
    const unsigned int* __restrict__ mbits, __half* __restrict__ av) {
  extern __shared__ __half smem[];
  __half* Ks = smem;                 // [NPAD][KSTR]
  __half* Vt = smem + LDS_K;         // [DH][VSTR]
  const int tid  = threadIdx.x;
  const int wave = tid >> 6, lane = tid & 63;
  const int lr   = lane & 15, lg = lane >> 4;
  __half* Pw = smem + LDS_K + LDS_V + wave * LDS_P;  // per-wave [16][PSTR]

  const int bh = blockIdx.x;
  const int b  = bh / NH, h = bh - b * NH;
  const int w  = b & (NWIN - 1);
  const size_t tbase = (size_t)b * NTOK;
  const int hoff = h * DH;

  for (int idx = tid; idx < NPAD * 4; idx += 512) {
    int j = idx >> 2, off = (idx & 3) << 3;
    half8 val = {0,0,0,0,0,0,0,0};
    if (j < NTOK) val = *reinterpret_cast<const half8*>(&qkvh[(tbase + j) * QKVF + CDIM + hoff + off]);
    *reinterpret_cast<half8*>(&Ks[j * KSTR + off]) = val;
  }
  for (int idx = tid; idx < NPAD * 4; idx += 512) {
    int j = idx >> 2, off = (idx & 3) << 3;
    if (j < NTOK) {
      union { float4 f; __half h[8]; } u;
      u.f = *reinterpret_cast<const float4*>(&qkvh[(tbase + j) * QKVF + 2 * CDIM + hoff + off]);
#pragma unroll
      for (int uu = 0; uu < 8; ++uu) Vt[(off + uu) * VSTR + j] = u.h[uu];
    } else {
#pragma unroll
      for (int uu = 0; uu < 8; ++uu) Vt[(off + uu) * VSTR + j] = __float2half(0.f);
    }
  }
  __syncthreads();

  const __half* bias_h = bias16 + (size_t)h * NN;
  const unsigned int* mb_w = mbits + (size_t)w * NTOK * MBW;

  for (int i0 = wave * 16; i0 < NPAD; i0 += 128) {
    int qrow = min(i0 + lr, NTOK - 1);
    half8 qa = *reinterpret_cast<const half8*>(&qkvh[(tbase + qrow) * QKVF + hoff + lg * 8]);

    int il[4];
#pragma unroll
    for (int r = 0; r < 4; ++r) il[r] = min(i0 + lg * 4 + r, NTOK - 1);

    f32x4 o0 = {0.f, 0.f, 0.f, 0.f}, o1 = {0.f, 0.f, 0.f, 0.f};
    float m[4]  = {-1e30f, -1e30f, -1e30f, -1e30f};
    float sm[4] = {0.f, 0.f, 0.f, 0.f};   // per-lane partial; one butterfly at end
    const f32x4 zf = {0.f, 0.f, 0.f, 0.f};

#pragma unroll
    for (int c = 0; c < 4; ++c) {
      const int njt = (c < 3) ? 6 : 4;   // chunk 3 covers keys 288..351
      const int nkt = (c < 3) ? 3 : 2;

      // QK^T for this chunk (C = 0)
      f32x4 s[6];
#pragma unroll
      for (int jl_ = 0; jl_ < njt; ++jl_) {
        int jt = c * 6 + jl_;
        half8 kb = *reinterpret_cast<const half8*>(&Ks[(jt * 16 + lr) * KSTR + lg * 8]);
        s[jl_] = __builtin_amdgcn_mfma_f32_16x16x32_f16(qa, kb, zf, 0, 0, 0);
      }

      // bias + mask + j-validity (identical ops to round 8)
#pragma unroll
      for (int jl_ = 0; jl_ < njt; ++jl_) {
        int jt = c * 6 + jl_;
        int j = jt * 16 + lr;
        bool vj = (jt < 21) || (lr < 7);      // j < 343
        int jl = vj ? j : (NTOK - 1);
        unsigned sh = (unsigned)(((jt & 1) << 4) + lr);
#pragma unroll
        for (int r = 0; r < 4; ++r) {
          float bm = __half2float(bias_h[(size_t)il[r] * NTOK + jl]);
          unsigned mwv = mb_w[il[r] * MBW + (jt >> 1)];
          float madd = ((mwv >> sh) & 1u) ? 0.f : -100.f;
          float val = s[jl_][r] + bm + madd;
          s[jl_][r] = vj ? val : -1e30f;
        }
      }

      // chunk row-max (16-lane butterfly)
      float pm[4] = {-1e30f, -1e30f, -1e30f, -1e30f};
#pragma unroll
      for (int jl_ = 0; jl_ < njt; ++jl_)
#pragma unroll
        for (int r = 0; r < 4; ++r) pm[r] = fmaxf(pm[r], s[jl_][r]);
#pragma unroll
      for (int off = 1; off <= 8; off <<= 1)
#pragma unroll
        for (int r = 0; r < 4; ++r) pm[r] = fmaxf(pm[r], __shfl_xor(pm[r], off));

      // online rescale (factor is lane-uniform per row)
#pragma unroll
      for (int r = 0; r < 4; ++r) {
        float mn = fmaxf(m[r], pm[r]);
        float f  = __expf(m[r] - mn);
        m[r] = mn;
        o0[r] *= f; o1[r] *= f; sm[r] *= f;
      }

      // exp + partial sum + P chunk -> LDS
#pragma unroll
      for (int jl_ = 0; jl_ < njt; ++jl_) {
#pragma unroll
        for (int r = 0; r < 4; ++r) {
          float p = __expf(s[jl_][r] - m[r]);
          sm[r] += p;
          Pw[(lg * 4 + r) * PSTR + jl_ * 16 + lr] = __float2half(p);
        }
      }
      asm volatile("s_waitcnt lgkmcnt(0)" ::: "memory");
      __builtin_amdgcn_sched_barrier(0);

      // PV for this chunk
#pragma unroll
      for (int ktl = 0; ktl < nkt; ++ktl) {
        int ktg = c * 3 + ktl;
        half8 pa  = *reinterpret_cast<const half8*>(&Pw[lr * PSTR + ktl * 32 + lg * 8]);
        half8 vb0 = *reinterpret_cast<const half8*>(&Vt[lr * VSTR + ktg * 32 + lg * 8]);
        half8 vb1 = *reinterpret_cast<const half8*>(&Vt[(16 + lr) * VSTR + ktg * 32 + lg * 8]);
        o0 = __builtin_amdgcn_mfma_f32_16x16x32_f16(pa, vb0, o0, 0, 0, 0);
        o1 = __builtin_amdgcn_mfma_f32_16x16x32_f16(pa, vb1, o1, 0, 0, 0);
      }
      __builtin_amdgcn_sched_barrier(0);   // keep chunk liveness separate
    }

    // final sum butterfly (sums were kept per-lane, rescaled consistently)
#pragma unroll
    for (int off = 1; off <= 8; off <<= 1)
#pragma unroll
      for (int r = 0; r < 4; ++r) sm[r] += __shfl_xor(sm[r], off);

#pragma unroll
    for (int r = 0; r < 4; ++r) {
      int i = i0 + lg * 4 + r;
      if (i < NTOK) {
        float inv = 1.f / sm[r];
        size_t ob = ((size_t)b * NTOK + i) * CDIM + hoff;
        av[ob + lr]      = __float2half(o0[r] * inv);
        av[ob + 16 + lr] = __float2half(o1[r] * inv);
      }
    }
  }
}

extern "C" void kernel_launch(void* const* d_in, const int* in_sizes, int n_in,
                              void* d_out, int out_size, void* d_ws, size_t ws_size,
                              hipStream_t stream) {
  const float* x          = (const float*)d_in[0];
  const float* mask       = (const float*)d_in[4];
  const float* w_qkv      = (const float*)d_in[6];
  const float* bias_table = (const float*)d_in[7];
  const float* w_proj     = (const float*)d_in[8];
  const float* b_proj     = (const float*)d_in[9];
  const int*   rel_index  = (const int*)d_in[10];
  float* out = (float*)d_out;

  // ws layout (~139.4 MB): qkvh [MTOK][1152] fp16, avb [MTOK][384] fp16
  // (aliased as xh during QKV), bias16 [12][NN] fp16, mbits, wqkvh, wprojh
  __half* qkvh   = (__half*)d_ws;
  __half* avb    = qkvh + (size_t)MTOK * QKVF;
  __half* xh     = avb;                                  // alias
  __half* bias16 = avb + (size_t)MTOK * CDIM;
  unsigned int* mbits = (unsigned int*)(bias16 + (size_t)NH * NN);
  __half* wqkvh  = (__half*)(mbits + (size_t)NWIN * NTOK * MBW);
  __half* wprojh = wqkvh + (size_t)QKVF * CDIM;

  const int NX = MTOK * CDIM;        // 16,859,136
  const int NWQ = QKVF * CDIM;       // 442,368
  const int NWP = CDIM * CDIM;       // 147,456
  cvt_f16_k<<<NX / 8 / 256, 256, 0, stream>>>(x, xh, NX);
  cvt_f16_k<<<NWQ / 8 / 256, 256, 0, stream>>>(w_qkv, wqkvh, NWQ);
  cvt_f16_k<<<NWP / 8 / 256, 256, 0, stream>>>(w_proj, wprojh, NWP);
  mask_pack_k<<<(NWIN * NTOK + 3) / 4, 256, 0, stream>>>(mask, mbits);
  bias_expand_k<<<(NN + 255) / 256, 256, 0, stream>>>(rel_index, bias_table, bias16);

  // QKV: A = xh, B = wqkvh, C = packed qkvh (fp16, q scaled)
  gemm_mfma_k<0><<<dim3(QKVF / 128, MTOK / 128), 256, 0, stream>>>(
      xh, wqkvh, nullptr, qkvh);

  (void)hipFuncSetAttribute((const void*)attn_k,
                            hipFuncAttributeMaxDynamicSharedMemorySize, LDS_TOT * 2);
  attn_k<<<BATCH * NH, 512, LDS_TOT * 2, stream>>>(qkvh, bias16, mbits, avb);

  // proj: A = avb (fp16), B = wprojh, C = out (fp32 + bias)
  gemm_mfma_k<1><<<dim3(CDIM / 128, MTOK / 128), 256, 0, stream>>>(
      avb, wprojh, b_proj, out);
}

// Round 13
// 316.783 us; speedup vs baseline: 2.0550x; 1.0465x over previous
//
#include <hip/hip_runtime.h>
#include <hip/hip_fp16.h>
#include <math.h>

#define BATCH 128
#define NTOK  343
#define NPAD  352
#define CDIM  384
#define NH    12
#define DH    32
#define NWIN  32
#define MTOK  (BATCH*NTOK)   // 43904
#define NN    (NTOK*NTOK)    // 117649
#define QKVF  (3*CDIM)       // 1152
#define KSTR  40             // attn K LDS row stride (halves)
#define VSTR  360
#define PSTR  106            // chunked P buffer stride (halves); conflict-verified
#define MBW   11             // u32 words per packed mask row
#define BTI   22             // bias_sw i-tiles
#define BJT   22             // bias_sw j-tiles
#define BSWT  (BTI*BJT*256)  // elements per head in bias_sw

typedef float    f32x4 __attribute__((ext_vector_type(4)));
typedef _Float16 half8 __attribute__((ext_vector_type(8)));
typedef _Float16 half4 __attribute__((ext_vector_type(4)));

#define LDS_K   (NPAD*KSTR)                 // 14080 halves = 28160 B
#define LDS_V   (DH*VSTR)                   // 11520 halves = 23040 B
#define LDS_P   (16*PSTR)                   // 1696 halves  = 3392 B per wave
#define LDS_TOT (LDS_K + LDS_V + 8*LDS_P)   // 39168 halves = 78336 B

// async global->LDS, 16B per lane; LDS dest = wave-uniform base + lane*16
__device__ __forceinline__ void gl2lds16(const __half* g, __half* l) {
  __builtin_amdgcn_global_load_lds(
      (const __attribute__((address_space(1))) void*)g,
      (__attribute__((address_space(3))) void*)l,
      16, 0, 0);
}

// ---------------- fp32 -> fp16 convert (8 elems/thread) ----------------
__global__ __launch_bounds__(256) void cvt_f16_k(
    const float* __restrict__ in, __half* __restrict__ out, int n) {
  int i = (blockIdx.x * 256 + threadIdx.x) * 8;
  if (i >= n) return;
  float4 a = *(const float4*)&in[i];
  float4 b = *(const float4*)&in[i + 4];
  half8 h;
  h[0] = (_Float16)a.x; h[1] = (_Float16)a.y; h[2] = (_Float16)a.z; h[3] = (_Float16)a.w;
  h[4] = (_Float16)b.x; h[5] = (_Float16)b.y; h[6] = (_Float16)b.z; h[7] = (_Float16)b.w;
  *(half8*)&out[i] = h;
}

// ---------------- bias gather -> fragment-order layout -----------------------
// bias_sw[h][ti][jt][lg][lr][r] = bias[h][ti*16+lg*4+r][jt*16+lr]
// invalid i or j -> -1000 (exp underflows to exact 0; deletes all vj selects)
__global__ __launch_bounds__(256) void bias_expand_k(
    const int* __restrict__ rel_index, const float* __restrict__ table,
    __half* __restrict__ bias_sw) {
  int t = blockIdx.x * 256 + threadIdx.x;   // t = (((ti*22+jt)*4+lg)*16+lr)*4+r
  if (t >= BSWT) return;
  int r  = t & 3;
  int lr = (t >> 2) & 15;
  int lg = (t >> 6) & 3;
  int jt = (t >> 8) % BJT;
  int ti = (t >> 8) / BJT;
  int i = ti * 16 + lg * 4 + r;
  int j = jt * 16 + lr;
  if (i < NTOK && j < NTOK) {
    int idx = rel_index[i * NTOK + j];
#pragma unroll
    for (int hh = 0; hh < NH; ++hh)
      bias_sw[(size_t)hh * BSWT + t] = __float2half(table[idx * NH + hh]);
  } else {
    __half pad = __float2half(-1000.0f);
#pragma unroll
    for (int hh = 0; hh < NH; ++hh)
      bias_sw[(size_t)hh * BSWT + t] = pad;
  }
}

// ---------------- mask bit-pack: bit=1 where mask==0 (allowed) ----------------
__global__ __launch_bounds__(256) void mask_pack_k(
    const float* __restrict__ mask, unsigned int* __restrict__ mbits) {
  int row = blockIdx.x * 4 + (threadIdx.x >> 6);
  int lane = threadIdx.x & 63;
  if (row >= NWIN * NTOK) return;
  const float* mr = mask + (size_t)row * NTOK;
#pragma unroll
  for (int seg = 0; seg < 6; ++seg) {
    int j = seg * 64 + lane;
    bool allowed = (j < NTOK) ? (mr[j] == 0.0f) : false;
    unsigned long long bits = __ballot(allowed);
    if (lane == 0) mbits[(size_t)row * MBW + seg*2] = (unsigned)bits;
    if (lane == 1 && seg*2 + 1 < MBW) mbits[(size_t)row * MBW + seg*2 + 1] = (unsigned)(bits >> 32);
  }
}

// ---------------- MFMA GEMM (all-fp16 inputs, global_load_lds staging) --------
// C[m,f] = sum_k A[m,k]*B[f,k]; 128x128 tile, BK=32, 4 waves, m97 2-barrier loop.
// EPI 0: packed qkv fp16 store (scale cols f<384).  EPI 1: fp32 out = acc+bias.
template<int EPI>
__global__ __launch_bounds__(256) void gemm_mfma_k(
    const __half* __restrict__ Ah, const __half* __restrict__ Bh,
    const float* __restrict__ bias, void* __restrict__ Cv) {
  __shared__ __half As[128 * 32];
  __shared__ __half Bs[128 * 32];
  const int tid  = threadIdx.x;
  const int lane = tid & 63, wave = tid >> 6;
  const int lr = lane & 15, lg = lane >> 4;
  const int wr = wave >> 1, wc = wave & 1;
  const int n0 = blockIdx.x * 128;
  const int m0 = blockIdx.y * 128;
  const int KD = 384;

  f32x4 acc[4][4];
#pragma unroll
  for (int i = 0; i < 4; ++i)
#pragma unroll
    for (int j = 0; j < 4; ++j) acc[i][j] = (f32x4){0.f, 0.f, 0.f, 0.f};

  for (int k0 = 0; k0 < KD; k0 += 32) {
#pragma unroll
    for (int i = 0; i < 2; ++i) {
      int cb = wave * 128 + i * 64;          // wave-uniform chunk base
      int c  = cb + lane;
      int row = c & 127, kg = c >> 7;
      gl2lds16(&Ah[(size_t)(m0 + row) * KD + k0 + kg * 8], &As[cb * 8]);
      gl2lds16(&Bh[(size_t)(n0 + row) * KD + k0 + kg * 8], &Bs[cb * 8]);
    }
    __syncthreads();

    half8 af[4], bf[4];
#pragma unroll
    for (int t = 0; t < 4; ++t) {
      af[t] = *(const half8*)&As[(lg * 128 + wr * 64 + t * 16 + lr) * 8];
      bf[t] = *(const half8*)&Bs[(lg * 128 + wc * 64 + t * 16 + lr) * 8];
    }
#pragma unroll
    for (int mi = 0; mi < 4; ++mi)
#pragma unroll
      for (int ni = 0; ni < 4; ++ni)
        acc[mi][ni] = __builtin_amdgcn_mfma_f32_16x16x32_f16(af[mi], bf[ni], acc[mi][ni], 0, 0, 0);
    __syncthreads();
  }

#pragma unroll
  for (int mi = 0; mi < 4; ++mi) {
#pragma unroll
    for (int r = 0; r < 4; ++r) {
      int m = m0 + wr * 64 + mi * 16 + lg * 4 + r;
#pragma unroll
      for (int ni = 0; ni < 4; ++ni) {
        int f = n0 + wc * 64 + ni * 16 + lr;
        float v = acc[mi][ni][r];
        if (EPI == 0) {
          if (f < CDIM) v *= 0.17677669529663687f;   // q scale
          ((__half*)Cv)[(size_t)m * QKVF + f] = __float2half(v);
        } else {
          ((float*)Cv)[(size_t)m * CDIM + f] = v + bias[f];
        }
      }
    }
  }
}

// ---------------- MFMA attention: 1 block per (b,h), 8 waves ----------------
// round-8 structure (monolithic s[22] softmax, chunked P->PV). ONLY change:
// bias via fragment-order layout -> 22 coalesced half4 loads, no vj selects.
__global__ __launch_bounds__(512, 1) void attn_k(
    const __half* __restrict__ qkvh, const __half* __restrict__ bias_sw,
    const unsigned int* __restrict__ mbits, __half* __restrict__ av) {
  extern __shared__ __half smem[];
  __half* Ks = smem;                 // [NPAD][KSTR]
  __half* Vt = smem + LDS_K;         // [DH][VSTR]
  const int tid  = threadIdx.x;
  const int wave = tid >> 6, lane = tid & 63;
  const int lr   = lane & 15, lg = lane >> 4;
  __half* Pw = smem + LDS_K + LDS_V + wave * LDS_P;  // per-wave [16][PSTR]

  const int bh = blockIdx.x;
  const int b  = bh / NH, h = bh - b * NH;
  const int w  = b & (NWIN - 1);
  const size_t tbase = (size_t)b * NTOK;
  const int hoff = h * DH;

  for (int idx = tid; idx < NPAD * 4; idx += 512) {
    int j = idx >> 2, off = (idx & 3) << 3;
    half8 val = {0,0,0,0,0,0,0,0};
    if (j < NTOK) val = *reinterpret_cast<const half8*>(&qkvh[(tbase + j) * QKVF + CDIM + hoff + off]);
    *reinterpret_cast<half8*>(&Ks[j * KSTR + off]) = val;
  }
  for (int idx = tid; idx < NPAD * 4; idx += 512) {
    int j = idx >> 2, off = (idx & 3) << 3;
    if (j < NTOK) {
      union { float4 f; __half h[8]; } u;
      u.f = *reinterpret_cast<const float4*>(&qkvh[(tbase + j) * QKVF + 2 * CDIM + hoff + off]);
#pragma unroll
      for (int uu = 0; uu < 8; ++uu) Vt[(off + uu) * VSTR + j] = u.h[uu];
    } else {
#pragma unroll
      for (int uu = 0; uu < 8; ++uu) Vt[(off + uu) * VSTR + j] = __float2half(0.f);
    }
  }
  __syncthreads();

  const __half* bias_h = bias_sw + (size_t)h * BSWT;
  const unsigned int* mb_w = mbits + (size_t)w * NTOK * MBW;
  const int lgofs = lg * 64 + lr * 4;       // per-lane bias offset within a jt

  for (int i0 = wave * 16; i0 < NPAD; i0 += 128) {
    int qrow = min(i0 + lr, NTOK - 1);
    half8 qa = *reinterpret_cast<const half8*>(&qkvh[(tbase + qrow) * QKVF + hoff + lg * 8]);

    // QK^T: 22 j-tiles
    f32x4 s[22];
    const f32x4 zf = {0.f, 0.f, 0.f, 0.f};
#pragma unroll
    for (int jt = 0; jt < 22; ++jt) {
      half8 kb = *reinterpret_cast<const half8*>(&Ks[(jt * 16 + lr) * KSTR + lg * 8]);
      s[jt] = __builtin_amdgcn_mfma_f32_16x16x32_f16(qa, kb, zf, 0, 0, 0);
    }

    int il[4];
#pragma unroll
    for (int r = 0; r < 4; ++r) il[r] = min(i0 + lg * 4 + r, NTOK - 1);

    // bias (coalesced half4, fragment-order layout) + mask (round-8 path).
    // invalid i/j carry bias=-1000 -> exp underflows to exact 0; no selects.
    const __half* bias_t = bias_h + (size_t)(i0 >> 4) * (BJT * 256) + lgofs;
#pragma unroll
    for (int jt = 0; jt < 22; ++jt) {
      half4 bt = *(const half4*)&bias_t[jt * 256];
      unsigned sh = (unsigned)(((jt & 1) << 4) + lr);
#pragma unroll
      for (int r = 0; r < 4; ++r) {
        unsigned mwv = mb_w[il[r] * MBW + (jt >> 1)];
        float madd = ((mwv >> sh) & 1u) ? 0.f : -100.f;
        s[jt][r] += (float)bt[r] + madd;
      }
    }

    float mx[4] = {-1e30f, -1e30f, -1e30f, -1e30f};
#pragma unroll
    for (int jt = 0; jt < 22; ++jt)
#pragma unroll
      for (int r = 0; r < 4; ++r) mx[r] = fmaxf(mx[r], s[jt][r]);
#pragma unroll
    for (int off = 1; off <= 8; off <<= 1)
#pragma unroll
      for (int r = 0; r < 4; ++r) mx[r] = fmaxf(mx[r], __shfl_xor(mx[r], off));
    float sm[4] = {0.f, 0.f, 0.f, 0.f};
#pragma unroll
    for (int jt = 0; jt < 22; ++jt)
#pragma unroll
      for (int r = 0; r < 4; ++r) {
        float p = __expf(s[jt][r] - mx[r]);
        s[jt][r] = p;
        sm[r] += p;
      }
#pragma unroll
    for (int off = 1; off <= 8; off <<= 1)
#pragma unroll
      for (int r = 0; r < 4; ++r) sm[r] += __shfl_xor(sm[r], off);

    // chunked P->LDS + PV: 4 chunks of <=96 keys through a [16][106] buffer
    f32x4 o0 = {0.f, 0.f, 0.f, 0.f}, o1 = {0.f, 0.f, 0.f, 0.f};
#pragma unroll
    for (int c = 0; c < 4; ++c) {
      const int njt = (c < 3) ? 6 : 4;     // chunk 3 covers keys 288..351
#pragma unroll
      for (int jtl = 0; jtl < njt; ++jtl) {
        int jt = c * 6 + jtl;
#pragma unroll
        for (int r = 0; r < 4; ++r)
          Pw[(lg * 4 + r) * PSTR + jtl * 16 + lr] = __float2half(s[jt][r]);
      }
      asm volatile("s_waitcnt lgkmcnt(0)" ::: "memory");
      __builtin_amdgcn_sched_barrier(0);
      const int nkt = (c < 3) ? 3 : 2;
#pragma unroll
      for (int ktl = 0; ktl < nkt; ++ktl) {
        int ktg = c * 3 + ktl;
        half8 pa  = *reinterpret_cast<const half8*>(&Pw[lr * PSTR + ktl * 32 + lg * 8]);
        half8 vb0 = *reinterpret_cast<const half8*>(&Vt[lr * VSTR + ktg * 32 + lg * 8]);
        half8 vb1 = *reinterpret_cast<const half8*>(&Vt[(16 + lr) * VSTR + ktg * 32 + lg * 8]);
        o0 = __builtin_amdgcn_mfma_f32_16x16x32_f16(pa, vb0, o0, 0, 0, 0);
        o1 = __builtin_amdgcn_mfma_f32_16x16x32_f16(pa, vb1, o1, 0, 0, 0);
      }
    }

#pragma unroll
    for (int r = 0; r < 4; ++r) {
      int i = i0 + lg * 4 + r;
      if (i < NTOK) {
        float inv = 1.f / sm[r];
        size_t ob = ((size_t)b * NTOK + i) * CDIM + hoff;
        av[ob + lr]      = __float2half(o0[r] * inv);
        av[ob + 16 + lr] = __float2half(o1[r] * inv);
      }
    }
  }
}

extern "C" void kernel_launch(void* const* d_in, const int* in_sizes, int n_in,
                              void* d_out, int out_size, void* d_ws, size_t ws_size,
                              hipStream_t stream) {
  const float* x          = (const float*)d_in[0];
  const float* mask       = (const float*)d_in[4];
  const float* w_qkv      = (const float*)d_in[6];
  const float* bias_table = (const float*)d_in[7];
  const float* w_proj     = (const float*)d_in[8];
  const float* b_proj     = (const float*)d_in[9];
  const int*   rel_index  = (const int*)d_in[10];
  float* out = (float*)d_out;

  // ws (~139.6 MB): qkvh [MTOK][1152] fp16, avb [MTOK][384] fp16 (alias xh),
  // bias_sw [12][22*22*256] fp16, mbits, wqkvh, wprojh
  __half* qkvh   = (__half*)d_ws;
  __half* avb    = qkvh + (size_t)MTOK * QKVF;
  __half* xh     = avb;                                  // alias
  __half* bias_sw = avb + (size_t)MTOK * CDIM;
  unsigned int* mbits = (unsigned int*)(bias_sw + (size_t)NH * BSWT);
  __half* wqkvh  = (__half*)(mbits + (size_t)NWIN * NTOK * MBW);
  __half* wprojh = wqkvh + (size_t)QKVF * CDIM;

  const int NX = MTOK * CDIM;        // 16,859,136
  const int NWQ = QKVF * CDIM;       // 442,368
  const int NWP = CDIM * CDIM;       // 147,456
  cvt_f16_k<<<NX / 8 / 256, 256, 0, stream>>>(x, xh, NX);
  cvt_f16_k<<<NWQ / 8 / 256, 256, 0, stream>>>(w_qkv, wqkvh, NWQ);
  cvt_f16_k<<<NWP / 8 / 256, 256, 0, stream>>>(w_proj, wprojh, NWP);
  mask_pack_k<<<(NWIN * NTOK + 3) / 4, 256, 0, stream>>>(mask, mbits);
  bias_expand_k<<<(BSWT + 255) / 256, 256, 0, stream>>>(rel_index, bias_table, bias_sw);

  // QKV: A = xh, B = wqkvh, C = packed qkvh (fp16, q scaled)
  gemm_mfma_k<0><<<dim3(QKVF / 128, MTOK / 128), 256, 0, stream>>>(
      xh, wqkvh, nullptr, qkvh);

  (void)hipFuncSetAttribute((const void*)attn_k,
                            hipFuncAttributeMaxDynamicSharedMemorySize, LDS_TOT * 2);
  attn_k<<<BATCH * NH, 512, LDS_TOT * 2, stream>>>(qkvh, bias_sw, mbits, avb);

  // proj: A = avb (fp16), B = wprojh, C = out (fp32 + bias)
  gemm_mfma_k<1><<<dim3(CDIM / 128, MTOK / 128), 256, 0, stream>>>(
      avb, wprojh, b_proj, out);
}

// Round 14
// 305.629 us; speedup vs baseline: 2.1300x; 1.0365x over previous
//
#include <hip/hip_runtime.h>
#include <hip/hip_fp16.h>
#include <math.h>

#define BATCH 128
#define NTOK  343
#define NPAD  352
#define CDIM  384
#define NH    12
#define DH    32
#define NWIN  32
#define MTOK  (BATCH*NTOK)   // 43904
#define NN    (NTOK*NTOK)    // 117649
#define QKVF  (3*CDIM)       // 1152
#define KSTR  40             // attn K LDS row stride (halves)
#define VSTR  360
#define PSTR  106            // chunked P buffer stride (halves); conflict-verified
#define MBW   11             // u32 words per packed mask row
#define BTI   22             // bias_sw i-tiles
#define BJT   22             // bias_sw j-tiles
#define BSWT  (BTI*BJT*256)  // elements per head in bias_sw

typedef float    f32x4 __attribute__((ext_vector_type(4)));
typedef _Float16 half8 __attribute__((ext_vector_type(8)));
typedef _Float16 half4 __attribute__((ext_vector_type(4)));

#define LDS_K   (NPAD*KSTR)                 // 14080 halves = 28160 B
#define LDS_V   (DH*VSTR)                   // 11520 halves = 23040 B
#define LDS_P   (16*PSTR)                   // 1696 halves  = 3392 B per wave
#define LDS_TOT (LDS_K + LDS_V + 8*LDS_P)   // 39168 halves = 78336 B

// async global->LDS, 16B per lane; LDS dest = wave-uniform base + lane*16
__device__ __forceinline__ void gl2lds16(const __half* g, __half* l) {
  __builtin_amdgcn_global_load_lds(
      (const __attribute__((address_space(1))) void*)g,
      (__attribute__((address_space(3))) void*)l,
      16, 0, 0);
}

// ---------------- fp32 -> fp16 convert (8 elems/thread) ----------------
__global__ __launch_bounds__(256) void cvt_f16_k(
    const float* __restrict__ in, __half* __restrict__ out, int n) {
  int i = (blockIdx.x * 256 + threadIdx.x) * 8;
  if (i >= n) return;
  float4 a = *(const float4*)&in[i];
  float4 b = *(const float4*)&in[i + 4];
  half8 h;
  h[0] = (_Float16)a.x; h[1] = (_Float16)a.y; h[2] = (_Float16)a.z; h[3] = (_Float16)a.w;
  h[4] = (_Float16)b.x; h[5] = (_Float16)b.y; h[6] = (_Float16)b.z; h[7] = (_Float16)b.w;
  *(half8*)&out[i] = h;
}

// ---------------- bias gather -> fragment-order layout -----------------------
// bias_sw[h][ti][jt][lg][lr][r] = bias[h][ti*16+lg*4+r][jt*16+lr]
// invalid i or j -> -1000 (exp underflows to exact 0; deletes all vj selects)
__global__ __launch_bounds__(256) void bias_expand_k(
    const int* __restrict__ rel_index, const float* __restrict__ table,
    __half* __restrict__ bias_sw) {
  int t = blockIdx.x * 256 + threadIdx.x;   // t = (((ti*22+jt)*4+lg)*16+lr)*4+r
  if (t >= BSWT) return;
  int r  = t & 3;
  int lr = (t >> 2) & 15;
  int lg = (t >> 6) & 3;
  int jt = (t >> 8) % BJT;
  int ti = (t >> 8) / BJT;
  int i = ti * 16 + lg * 4 + r;
  int j = jt * 16 + lr;
  if (i < NTOK && j < NTOK) {
    int idx = rel_index[i * NTOK + j];
#pragma unroll
    for (int hh = 0; hh < NH; ++hh)
      bias_sw[(size_t)hh * BSWT + t] = __float2half(table[idx * NH + hh]);
  } else {
    __half pad = __float2half(-1000.0f);
#pragma unroll
    for (int hh = 0; hh < NH; ++hh)
      bias_sw[(size_t)hh * BSWT + t] = pad;
  }
}

// ---------------- mask bit-pack: bit=1 where mask==0 (allowed) ----------------
__global__ __launch_bounds__(256) void mask_pack_k(
    const float* __restrict__ mask, unsigned int* __restrict__ mbits) {
  int row = blockIdx.x * 4 + (threadIdx.x >> 6);
  int lane = threadIdx.x & 63;
  if (row >= NWIN * NTOK) return;
  const float* mr = mask + (size_t)row * NTOK;
#pragma unroll
  for (int seg = 0; seg < 6; ++seg) {
    int j = seg * 64 + lane;
    bool allowed = (j < NTOK) ? (mr[j] == 0.0f) : false;
    unsigned long long bits = __ballot(allowed);
    if (lane == 0) mbits[(size_t)row * MBW + seg*2] = (unsigned)bits;
    if (lane == 1 && seg*2 + 1 < MBW) mbits[(size_t)row * MBW + seg*2 + 1] = (unsigned)(bits >> 32);
  }
}

// ---------------- MFMA GEMM (all-fp16, gl2lds staging, BK=64, XCD swizzle) ----
// C[m,f] = sum_k A[m,k]*B[f,k]; 128x128 tile, BK=64, 4 waves.
// 6 barrier-drains per block (vs 12 at BK=32). Bijective XCD swizzle (m204)
// co-locates blocks sharing an A-panel on one XCD's L2.
// EPI 0: packed qkv fp16 store (scale cols f<384).  EPI 1: fp32 out = acc+bias.
template<int EPI>
__global__ __launch_bounds__(256) void gemm_mfma_k(
    const __half* __restrict__ Ah, const __half* __restrict__ Bh,
    const float* __restrict__ bias, void* __restrict__ Cv) {
  __shared__ __half As[1024 * 8];   // [kg 8][row 128][8]  = 16 KB
  __shared__ __half Bs[1024 * 8];
  const int tid  = threadIdx.x;
  const int lane = tid & 63, wave = tid >> 6;
  const int lr = lane & 15, lg = lane >> 4;
  const int wr = wave >> 1, wc = wave & 1;

  // XCD-bijective swizzle of the flat block id (m204)
  const int nwg = gridDim.x * gridDim.y;
  const int flat = blockIdx.y * gridDim.x + blockIdx.x;
  const int q = nwg >> 3, rr = nwg & 7;
  const int xcd = flat & 7, lid = flat >> 3;
  const int swz = (xcd < rr ? xcd * (q + 1) : rr * (q + 1) + (xcd - rr) * q) + lid;
  const int n0 = (swz % gridDim.x) * 128;
  const int m0 = (swz / gridDim.x) * 128;
  const int KD = 384;

  f32x4 acc[4][4];
#pragma unroll
  for (int i = 0; i < 4; ++i)
#pragma unroll
    for (int j = 0; j < 4; ++j) acc[i][j] = (f32x4){0.f, 0.f, 0.f, 0.f};

  for (int k0 = 0; k0 < KD; k0 += 64) {
    // stage 64-wide K-slab: 1024 chunks of 16B per operand; 4 issues/wave each
#pragma unroll
    for (int i = 0; i < 4; ++i) {
      int cb = wave * 256 + i * 64;          // wave-uniform chunk base
      int c  = cb + lane;
      int row = c & 127, kg = c >> 7;        // kg 0..7
      gl2lds16(&Ah[(size_t)(m0 + row) * KD + k0 + kg * 8], &As[cb * 8]);
      gl2lds16(&Bh[(size_t)(n0 + row) * KD + k0 + kg * 8], &Bs[cb * 8]);
    }
    __syncthreads();

#pragma unroll
    for (int kk = 0; kk < 2; ++kk) {         // two K=32 halves
      const int kg = lg + kk * 4;
      half8 af[4], bf[4];
#pragma unroll
      for (int t = 0; t < 4; ++t) {
        af[t] = *(const half8*)&As[(kg * 128 + wr * 64 + t * 16 + lr) * 8];
        bf[t] = *(const half8*)&Bs[(kg * 128 + wc * 64 + t * 16 + lr) * 8];
      }
#pragma unroll
      for (int mi = 0; mi < 4; ++mi)
#pragma unroll
        for (int ni = 0; ni < 4; ++ni)
          acc[mi][ni] = __builtin_amdgcn_mfma_f32_16x16x32_f16(af[mi], bf[ni], acc[mi][ni], 0, 0, 0);
    }
    __syncthreads();
  }

#pragma unroll
  for (int mi = 0; mi < 4; ++mi) {
#pragma unroll
    for (int r = 0; r < 4; ++r) {
      int m = m0 + wr * 64 + mi * 16 + lg * 4 + r;
#pragma unroll
      for (int ni = 0; ni < 4; ++ni) {
        int f = n0 + wc * 64 + ni * 16 + lr;
        float v = acc[mi][ni][r];
        if (EPI == 0) {
          if (f < CDIM) v *= 0.17677669529663687f;   // q scale
          ((__half*)Cv)[(size_t)m * QKVF + f] = __float2half(v);
        } else {
          ((float*)Cv)[(size_t)m * CDIM + f] = v + bias[f];
        }
      }
    }
  }
}

// ---------------- MFMA attention: 1 block per (b,h), 8 waves (round-13) ------
__global__ __launch_bounds__(512, 1) void attn_k(
    const __half* __restrict__ qkvh, const __half* __restrict__ bias_sw,
    const unsigned int* __restrict__ mbits, __half* __restrict__ av) {
  extern __shared__ __half smem[];
  __half* Ks = smem;                 // [NPAD][KSTR]
  __half* Vt = smem + LDS_K;         // [DH][VSTR]
  const int tid  = threadIdx.x;
  const int wave = tid >> 6, lane = tid & 63;
  const int lr   = lane & 15, lg = lane >> 4;
  __half* Pw = smem + LDS_K + LDS_V + wave * LDS_P;  // per-wave [16][PSTR]

  const int bh = blockIdx.x;
  const int b  = bh / NH, h = bh - b * NH;
  const int w  = b & (NWIN - 1);
  const size_t tbase = (size_t)b * NTOK;
  const int hoff = h * DH;

  for (int idx = tid; idx < NPAD * 4; idx += 512) {
    int j = idx >> 2, off = (idx & 3) << 3;
    half8 val = {0,0,0,0,0,0,0,0};
    if (j < NTOK) val = *reinterpret_cast<const half8*>(&qkvh[(tbase + j) * QKVF + CDIM + hoff + off]);
    *reinterpret_cast<half8*>(&Ks[j * KSTR + off]) = val;
  }
  for (int idx = tid; idx < NPAD * 4; idx += 512) {
    int j = idx >> 2, off = (idx & 3) << 3;
    if (j < NTOK) {
      union { float4 f; __half h[8]; } u;
      u.f = *reinterpret_cast<const float4*>(&qkvh[(tbase + j) * QKVF + 2 * CDIM + hoff + off]);
#pragma unroll
      for (int uu = 0; uu < 8; ++uu) Vt[(off + uu) * VSTR + j] = u.h[uu];
    } else {
#pragma unroll
      for (int uu = 0; uu < 8; ++uu) Vt[(off + uu) * VSTR + j] = __float2half(0.f);
    }
  }
  __syncthreads();

  const __half* bias_h = bias_sw + (size_t)h * BSWT;
  const unsigned int* mb_w = mbits + (size_t)w * NTOK * MBW;
  const int lgofs = lg * 64 + lr * 4;       // per-lane bias offset within a jt

  for (int i0 = wave * 16; i0 < NPAD; i0 += 128) {
    int qrow = min(i0 + lr, NTOK - 1);
    half8 qa = *reinterpret_cast<const half8*>(&qkvh[(tbase + qrow) * QKVF + hoff + lg * 8]);

    // QK^T: 22 j-tiles
    f32x4 s[22];
    const f32x4 zf = {0.f, 0.f, 0.f, 0.f};
#pragma unroll
    for (int jt = 0; jt < 22; ++jt) {
      half8 kb = *reinterpret_cast<const half8*>(&Ks[(jt * 16 + lr) * KSTR + lg * 8]);
      s[jt] = __builtin_amdgcn_mfma_f32_16x16x32_f16(qa, kb, zf, 0, 0, 0);
    }

    int il[4];
#pragma unroll
    for (int r = 0; r < 4; ++r) il[r] = min(i0 + lg * 4 + r, NTOK - 1);

    // bias (coalesced half4, fragment-order layout) + mask (round-8 path).
    const __half* bias_t = bias_h + (size_t)(i0 >> 4) * (BJT * 256) + lgofs;
#pragma unroll
    for (int jt = 0; jt < 22; ++jt) {
      half4 bt = *(const half4*)&bias_t[jt * 256];
      unsigned sh = (unsigned)(((jt & 1) << 4) + lr);
#pragma unroll
      for (int r = 0; r < 4; ++r) {
        unsigned mwv = mb_w[il[r] * MBW + (jt >> 1)];
        float madd = ((mwv >> sh) & 1u) ? 0.f : -100.f;
        s[jt][r] += (float)bt[r] + madd;
      }
    }

    float mx[4] = {-1e30f, -1e30f, -1e30f, -1e30f};
#pragma unroll
    for (int jt = 0; jt < 22; ++jt)
#pragma unroll
      for (int r = 0; r < 4; ++r) mx[r] = fmaxf(mx[r], s[jt][r]);
#pragma unroll
    for (int off = 1; off <= 8; off <<= 1)
#pragma unroll
      for (int r = 0; r < 4; ++r) mx[r] = fmaxf(mx[r], __shfl_xor(mx[r], off));
    float sm[4] = {0.f, 0.f, 0.f, 0.f};
#pragma unroll
    for (int jt = 0; jt < 22; ++jt)
#pragma unroll
      for (int r = 0; r < 4; ++r) {
        float p = __expf(s[jt][r] - mx[r]);
        s[jt][r] = p;
        sm[r] += p;
      }
#pragma unroll
    for (int off = 1; off <= 8; off <<= 1)
#pragma unroll
      for (int r = 0; r < 4; ++r) sm[r] += __shfl_xor(sm[r], off);

    // chunked P->LDS + PV: 4 chunks of <=96 keys through a [16][106] buffer
    f32x4 o0 = {0.f, 0.f, 0.f, 0.f}, o1 = {0.f, 0.f, 0.f, 0.f};
#pragma unroll
    for (int c = 0; c < 4; ++c) {
      const int njt = (c < 3) ? 6 : 4;     // chunk 3 covers keys 288..351
#pragma unroll
      for (int jtl = 0; jtl < njt; ++jtl) {
        int jt = c * 6 + jtl;
#pragma unroll
        for (int r = 0; r < 4; ++r)
          Pw[(lg * 4 + r) * PSTR + jtl * 16 + lr] = __float2half(s[jt][r]);
      }
      asm volatile("s_waitcnt lgkmcnt(0)" ::: "memory");
      __builtin_amdgcn_sched_barrier(0);
      const int nkt = (c < 3) ? 3 : 2;
#pragma unroll
      for (int ktl = 0; ktl < nkt; ++ktl) {
        int ktg = c * 3 + ktl;
        half8 pa  = *reinterpret_cast<const half8*>(&Pw[lr * PSTR + ktl * 32 + lg * 8]);
        half8 vb0 = *reinterpret_cast<const half8*>(&Vt[lr * VSTR + ktg * 32 + lg * 8]);
        half8 vb1 = *reinterpret_cast<const half8*>(&Vt[(16 + lr) * VSTR + ktg * 32 + lg * 8]);
        o0 = __builtin_amdgcn_mfma_f32_16x16x32_f16(pa, vb0, o0, 0, 0, 0);
        o1 = __builtin_amdgcn_mfma_f32_16x16x32_f16(pa, vb1, o1, 0, 0, 0);
      }
    }

#pragma unroll
    for (int r = 0; r < 4; ++r) {
      int i = i0 + lg * 4 + r;
      if (i < NTOK) {
        float inv = 1.f / sm[r];
        size_t ob = ((size_t)b * NTOK + i) * CDIM + hoff;
        av[ob + lr]      = __float2half(o0[r] * inv);
        av[ob + 16 + lr] = __float2half(o1[r] * inv);
      }
    }
  }
}

extern "C" void kernel_launch(void* const* d_in, const int* in_sizes, int n_in,
                              void* d_out, int out_size, void* d_ws, size_t ws_size,
                              hipStream_t stream) {
  const float* x          = (const float*)d_in[0];
  const float* mask       = (const float*)d_in[4];
  const float* w_qkv      = (const float*)d_in[6];
  const float* bias_table = (const float*)d_in[7];
  const float* w_proj     = (const float*)d_in[8];
  const float* b_proj     = (const float*)d_in[9];
  const int*   rel_index  = (const int*)d_in[10];
  float* out = (float*)d_out;

  // ws (~139.6 MB): qkvh [MTOK][1152] fp16, avb [MTOK][384] fp16 (alias xh),
  // bias_sw [12][22*22*256] fp16, mbits, wqkvh, wprojh
  __half* qkvh   = (__half*)d_ws;
  __half* avb    = qkvh + (size_t)MTOK * QKVF;
  __half* xh     = avb;                                  // alias
  __half* bias_sw = avb + (size_t)MTOK * CDIM;
  unsigned int* mbits = (unsigned int*)(bias_sw + (size_t)NH * BSWT);
  __half* wqkvh  = (__half*)(mbits + (size_t)NWIN * NTOK * MBW);
  __half* wprojh = wqkvh + (size_t)QKVF * CDIM;

  const int NX = MTOK * CDIM;        // 16,859,136
  const int NWQ = QKVF * CDIM;       // 442,368
  const int NWP = CDIM * CDIM;       // 147,456
  cvt_f16_k<<<NX / 8 / 256, 256, 0, stream>>>(x, xh, NX);
  cvt_f16_k<<<NWQ / 8 / 256, 256, 0, stream>>>(w_qkv, wqkvh, NWQ);
  cvt_f16_k<<<NWP / 8 / 256, 256, 0, stream>>>(w_proj, wprojh, NWP);
  mask_pack_k<<<(NWIN * NTOK + 3) / 4, 256, 0, stream>>>(mask, mbits);
  bias_expand_k<<<(BSWT + 255) / 256, 256, 0, stream>>>(rel_index, bias_table, bias_sw);

  // QKV: A = xh, B = wqkvh, C = packed qkvh (fp16, q scaled)
  gemm_mfma_k<0><<<dim3(QKVF / 128, MTOK / 128), 256, 0, stream>>>(
      xh, wqkvh, nullptr, qkvh);

  (void)hipFuncSetAttribute((const void*)attn_k,
                            hipFuncAttributeMaxDynamicSharedMemorySize, LDS_TOT * 2);
  attn_k<<<BATCH * NH, 512, LDS_TOT * 2, stream>>>(qkvh, bias_sw, mbits, avb);

  // proj: A = avb (fp16), B = wprojh, C = out (fp32 + bias)
  gemm_mfma_k<1><<<dim3(CDIM / 128, MTOK / 128), 256, 0, stream>>>(
      avb, wprojh, b_proj, out);
}